// Round 1
// baseline (986.432 us; speedup 1.0000x reference)
//
#include <hip/hip_runtime.h>
#include <math.h>

#define BB 32
#define NN 32
#define XSS 256
#define KSS 128
#define DD 1024
#define VV 32000
#define TAU_INV 10000.0f

typedef int mask_t;  // bool inputs assumed delivered as int32 per harness doc ("integer -> const int*")

// ---- workspace layout (float offsets) ----
#define WS_MEANX   0                       // 32*1024
#define WS_MEANY   32768                   // 32*1024
#define WS_MEANK   65536                   // 32*32*1024
#define WS_XCATY   1114112                 // 32*1024
#define WS_VPRE    1146880                 // 32*1024
#define WS_NNZ_CNT 1179648                 // int[32]
#define WS_NNZ_IDX 1179680                 // int[32*32]
#define WS_NNZ_W   1180704                 // float[32*32]
#define WS_LSM_M   1181728                 // float[32*16]
#define WS_LSM_S   1182240                 // float[32*16]
#define WS_LSE     1182752                 // float[32]

// ---- output layout (float offsets) ----
#define OUT_PRIOR  0
#define OUT_POST   (BB*NN)
#define OUT_KIDX   (2*BB*NN)
#define OUT_SEL    (3*BB*NN)
#define OUT_VOCAB  (3*BB*NN + BB*KSS*DD)

__device__ __forceinline__ float dot4(float4 a, float4 b) {
  return a.x*b.x + a.y*b.y + a.z*b.z + a.w*b.w;
}

// mean_X / mean_Y: grid (8 chunks, 32 b, 2 which), block 256, float4 over D
__global__ void k_meanxy(const float4* __restrict__ U, const float4* __restrict__ R,
                         const mask_t* __restrict__ um, const mask_t* __restrict__ rm,
                         float* __restrict__ ws) {
  const int chunk = blockIdx.x, b = blockIdx.y, which = blockIdx.z, t = threadIdx.x;
  const float4* src = which ? R : U;
  const mask_t* m = which ? rm : um;
  float* dst = ws + (which ? WS_MEANY : WS_MEANX) + b * DD;
  float4 acc = make_float4(0.f, 0.f, 0.f, 0.f);
  const int x0 = chunk * 32;
  for (int x = x0; x < x0 + 32; ++x) {
    if (!m[b * XSS + x]) {
      float4 v = src[(x * BB + b) * (DD/4) + t];
      acc.x += v.x; acc.y += v.y; acc.z += v.z; acc.w += v.w;
    }
  }
  const float s = 1.0f / XSS;
  atomicAdd(&dst[t*4+0], acc.x * s);
  atomicAdd(&dst[t*4+1], acc.y * s);
  atomicAdd(&dst[t*4+2], acc.z * s);
  atomicAdd(&dst[t*4+3], acc.w * s);
}

// mean_K: grid (N, B), block 256. THE dominant kernel: streams 537MB (skips ~10% masked rows).
__global__ void k_meank(const float4* __restrict__ K, const mask_t* __restrict__ km,
                        float* __restrict__ ws) {
  const int n = blockIdx.x, b = blockIdx.y, t = threadIdx.x;
  const mask_t* mrow = km + (b * NN + n) * KSS;
  float4 acc = make_float4(0.f, 0.f, 0.f, 0.f);
  #pragma unroll 2
  for (int s = 0; s < KSS; ++s) {
    if (!mrow[s]) {
      float4 v = K[((n * KSS + s) * BB + b) * (DD/4) + t];
      acc.x += v.x; acc.y += v.y; acc.z += v.z; acc.w += v.w;
    }
  }
  const float sc = 1.0f / KSS;
  float4* out = (float4*)(ws + WS_MEANK) + (b * NN + n) * (DD/4);
  out[t] = make_float4(acc.x*sc, acc.y*sc, acc.z*sc, acc.w*sc);
}

// X_cat_Y = concat(meanX, meanY) @ W1.T + b1 : grid 128, block 256 (lane=b, broadcast W1)
__global__ void k_xcaty(const float4* __restrict__ W1, const float* __restrict__ b1,
                        float* __restrict__ ws) {
  const int t = threadIdx.x;
  const int b = t & 31;
  const int d = blockIdx.x * 8 + (t >> 5);
  const float4* mx = (const float4*)(ws + WS_MEANX) + b * (DD/4);
  const float4* my = (const float4*)(ws + WS_MEANY) + b * (DD/4);
  const float4* w  = W1 + d * (2 * DD / 4);
  float acc = b1[d];
  #pragma unroll 4
  for (int q = 0; q < DD/4; ++q) acc += dot4(w[q], mx[q]);
  #pragma unroll 4
  for (int q = 0; q < DD/4; ++q) acc += dot4(w[DD/4 + q], my[q]);
  ws[WS_XCATY + b * DD + d] = acc;
}

// per-b fused small stage: prior, posterior, K_index, vocab_pre, nnz list. grid 32, block 256.
__global__ void k_small(const float* __restrict__ gumbel, float* __restrict__ ws,
                        float* __restrict__ out) {
  const int b = blockIdx.x, t = threadIdx.x;
  const int lane = t & 63, wid = t >> 6;
  __shared__ float redp[4], redq[4];
  __shared__ float plp[NN], plq[NN], kw[NN];
  __shared__ float scal[3];  // lse1, m2, s2
  __shared__ int   nnz_idx_s[NN];
  __shared__ float nnz_w_s[NN];
  __shared__ int   nnz_cnt_s;

  const float4* mk = (const float4*)(ws + WS_MEANK) + b * NN * (DD/4);
  const float4 mxr = ((const float4*)(ws + WS_MEANX))[b * (DD/4) + t];
  const float4 xyr = ((const float4*)(ws + WS_XCATY))[b * (DD/4) + t];

  for (int n = 0; n < NN; ++n) {
    float4 mkv = mk[n * (DD/4) + t];
    float pp = dot4(mkv, mxr);
    float qq = dot4(mkv, xyr);
    for (int off = 32; off > 0; off >>= 1) {
      pp += __shfl_down(pp, off);
      qq += __shfl_down(qq, off);
    }
    if (lane == 0) { redp[wid] = pp; redq[wid] = qq; }
    __syncthreads();
    if (t == 0) {
      plp[n] = redp[0] + redp[1] + redp[2] + redp[3];
      plq[n] = redq[0] + redq[1] + redq[2] + redq[3];
    }
    __syncthreads();
  }

  if (t == 0) {
    float z[NN];
    float m1 = -1e30f, m2 = -1e30f, m3 = -1e30f;
    for (int n = 0; n < NN; ++n) {
      m1 = fmaxf(m1, plp[n]);
      m2 = fmaxf(m2, plq[n]);
      z[n] = plq[n] + gumbel[b * NN + n];
      m3 = fmaxf(m3, z[n]);
    }
    float s1 = 0.f, s2 = 0.f, s3 = 0.f;
    for (int n = 0; n < NN; ++n) {
      s1 += expf(plp[n] - m1);
      s2 += expf(plq[n] - m2);
      float w = expf((z[n] - m3) * TAU_INV);
      kw[n] = w;
      s3 += w;
    }
    scal[0] = m1 + logf(s1);
    scal[1] = m2;
    scal[2] = s2;
    const float inv3 = 1.0f / s3;
    int cnt = 0;
    for (int n = 0; n < NN; ++n) {
      kw[n] *= inv3;
      if (kw[n] > 0.f) { nnz_idx_s[cnt] = n; nnz_w_s[cnt] = kw[n]; ++cnt; }
    }
    nnz_cnt_s = cnt;
    ((int*)(ws + WS_NNZ_CNT))[b] = cnt;
    for (int j = 0; j < cnt; ++j) {
      ((int*)(ws + WS_NNZ_IDX))[b * NN + j] = nnz_idx_s[j];
      ws[WS_NNZ_W + b * NN + j] = nnz_w_s[j];
    }
  }
  __syncthreads();

  if (t < NN) {
    out[OUT_PRIOR + b * NN + t] = plp[t] - scal[0];
    out[OUT_POST  + b * NN + t] = expf(plq[t] - scal[1]) / scal[2];
    out[OUT_KIDX  + b * NN + t] = kw[t];
  }

  // vocab_pre = sum_n kidx[n] * mean_K[b,n,:]
  float4 acc = make_float4(0.f, 0.f, 0.f, 0.f);
  const int cnt = nnz_cnt_s;
  for (int j = 0; j < cnt; ++j) {
    const float w = nnz_w_s[j];
    float4 v = mk[nnz_idx_s[j] * (DD/4) + t];
    acc.x += w * v.x; acc.y += w * v.y; acc.z += w * v.z; acc.w += w * v.w;
  }
  ((float4*)(ws + WS_VPRE))[b * (DD/4) + t] = acc;
}

// selected_K: grid (KS, B), block 256; gather only nonzero-weight n's.
__global__ void k_selected(const float4* __restrict__ K, const mask_t* __restrict__ km,
                           const float* __restrict__ ws, float4* __restrict__ outsel) {
  const int s = blockIdx.x, b = blockIdx.y, t = threadIdx.x;
  const int cnt = ((const int*)(ws + WS_NNZ_CNT))[b];
  float4 acc = make_float4(0.f, 0.f, 0.f, 0.f);
  for (int j = 0; j < cnt; ++j) {
    const int n = ((const int*)(ws + WS_NNZ_IDX))[b * NN + j];
    const float w = ws[WS_NNZ_W + b * NN + j];
    if (!km[(b * NN + n) * KSS + s]) {
      float4 v = K[((n * KSS + s) * BB + b) * (DD/4) + t];
      acc.x += w * v.x; acc.y += w * v.y; acc.z += w * v.z; acc.w += w * v.w;
    }
  }
  outsel[(b * KSS + s) * (DD/4) + t] = acc;
}

// vocab GEMM: logits[b,v] += dot(vpre[b], W2[v]) over this block's e-half.
// grid (125, 2), block 256. Tile 256v x 32b, thread tile 8v x 4b, e-tile 32.
__global__ void __launch_bounds__(256) k_vocab(const float4* __restrict__ W2,
                                               const float* __restrict__ ws,
                                               float* __restrict__ logits) {
  const int t = threadIdx.x;
  const int V0 = blockIdx.x * 256;
  const int e4_base = blockIdx.y * 128;   // float4 units (512 floats per half)
  __shared__ float4 w2s[256 * 9];
  __shared__ float4 pres[32 * 9];
  const float4* vp = (const float4*)(ws + WS_VPRE);
  const int vlane = t & 31, bgrp = t >> 5;

  float acc[8][4];
  #pragma unroll
  for (int k = 0; k < 8; ++k)
    #pragma unroll
    for (int j = 0; j < 4; ++j) acc[k][j] = 0.f;

  for (int e4 = e4_base; e4 < e4_base + 128; e4 += 8) {
    #pragma unroll
    for (int k = 0; k < 8; ++k) {
      const int f = t + 256 * k;
      const int vr = f >> 3, q = f & 7;
      w2s[vr * 9 + q] = W2[(V0 + vr) * (DD/4) + e4 + q];
    }
    {
      const int br = t >> 3, q = t & 7;
      pres[br * 9 + q] = vp[br * (DD/4) + e4 + q];
    }
    __syncthreads();
    #pragma unroll
    for (int q = 0; q < 8; ++q) {
      float4 pb[4];
      #pragma unroll
      for (int j = 0; j < 4; ++j) pb[j] = pres[(bgrp + 8 * j) * 9 + q];
      #pragma unroll
      for (int k = 0; k < 8; ++k) {
        float4 wv = w2s[(vlane + 32 * k) * 9 + q];
        #pragma unroll
        for (int j = 0; j < 4; ++j) acc[k][j] += dot4(wv, pb[j]);
      }
    }
    __syncthreads();
  }
  #pragma unroll
  for (int k = 0; k < 8; ++k)
    #pragma unroll
    for (int j = 0; j < 4; ++j)
      atomicAdd(&logits[(bgrp + 8 * j) * VV + V0 + vlane + 32 * k], acc[k][j]);
}

// log_softmax over V: partial max/sumexp per (b, chunk). grid (16, 32), block 256.
__global__ void k_lsm1(const float* __restrict__ logits, const float* __restrict__ b2,
                       float* __restrict__ ws) {
  const int c = blockIdx.x, b = blockIdx.y, t = threadIdx.x;
  const int lane = t & 63, wid = t >> 6;
  const float* base = logits + b * VV + c * 2000;
  const float* bb = b2 + c * 2000;
  __shared__ float red[4];
  float xv[8];
  int cnt = 0;
  float m = -1e30f;
  for (int i = t; i < 2000; i += 256) {
    float x = base[i] + bb[i];
    xv[cnt++] = x;
    m = fmaxf(m, x);
  }
  for (int off = 32; off > 0; off >>= 1) m = fmaxf(m, __shfl_down(m, off));
  if (lane == 0) red[wid] = m;
  __syncthreads();
  if (t == 0) red[0] = fmaxf(fmaxf(red[0], red[1]), fmaxf(red[2], red[3]));
  __syncthreads();
  const float M = red[0];
  __syncthreads();
  float s = 0.f;
  for (int i = 0; i < cnt; ++i) s += expf(xv[i] - M);
  for (int off = 32; off > 0; off >>= 1) s += __shfl_down(s, off);
  if (lane == 0) red[wid] = s;
  __syncthreads();
  if (t == 0) {
    ws[WS_LSM_M + b * 16 + c] = M;
    ws[WS_LSM_S + b * 16 + c] = red[0] + red[1] + red[2] + red[3];
  }
}

// combine per-chunk partials -> lse[b]. grid 1, block 64.
__global__ void k_lsm2(float* __restrict__ ws) {
  const int t = threadIdx.x;
  if (t < BB) {
    float M = -1e30f;
    for (int c = 0; c < 16; ++c) M = fmaxf(M, ws[WS_LSM_M + t * 16 + c]);
    float S = 0.f;
    for (int c = 0; c < 16; ++c)
      S += ws[WS_LSM_S + t * 16 + c] * expf(ws[WS_LSM_M + t * 16 + c] - M);
    ws[WS_LSE + t] = M + logf(S);
  }
}

// finalize: out = raw + b2 - lse[b]. grid (125, 32), block 256.
__global__ void k_lsm3(const float* __restrict__ b2, const float* __restrict__ ws,
                       float* __restrict__ logits) {
  const int v = blockIdx.x * 256 + threadIdx.x;
  const int b = blockIdx.y;
  logits[b * VV + v] = logits[b * VV + v] + b2[v] - ws[WS_LSE + b];
}

extern "C" void kernel_launch(void* const* d_in, const int* in_sizes, int n_in,
                              void* d_out, int out_size, void* d_ws, size_t ws_size,
                              hipStream_t stream) {
  const float4* U  = (const float4*)d_in[0];
  const float4* R  = (const float4*)d_in[1];
  const float4* K  = (const float4*)d_in[2];
  const mask_t* um = (const mask_t*)d_in[3];
  const mask_t* rm = (const mask_t*)d_in[4];
  const mask_t* km = (const mask_t*)d_in[5];
  const float* g   = (const float*)d_in[6];
  const float4* W1 = (const float4*)d_in[7];
  const float* b1  = (const float*)d_in[8];
  const float4* W2 = (const float4*)d_in[9];
  const float* b2  = (const float*)d_in[10];
  float* out = (float*)d_out;
  float* ws  = (float*)d_ws;

  // zero-init atomic accumulation targets
  hipMemsetAsync(ws + WS_MEANX, 0, 2 * BB * DD * sizeof(float), stream);
  hipMemsetAsync(out + OUT_VOCAB, 0, (size_t)BB * VV * sizeof(float), stream);

  k_meanxy <<<dim3(8, 32, 2), 256, 0, stream>>>(U, R, um, rm, ws);
  k_meank  <<<dim3(NN, BB),   256, 0, stream>>>(K, km, ws);
  k_xcaty  <<<dim3(128),      256, 0, stream>>>(W1, b1, ws);
  k_small  <<<dim3(BB),       256, 0, stream>>>(g, ws, out);
  k_selected<<<dim3(KSS, BB), 256, 0, stream>>>(K, km, ws, (float4*)(out + OUT_SEL));
  k_vocab  <<<dim3(125, 2),   256, 0, stream>>>(W2, ws, out + OUT_VOCAB);
  k_lsm1   <<<dim3(16, BB),   256, 0, stream>>>(out + OUT_VOCAB, b2, ws);
  k_lsm2   <<<dim3(1),        64,  0, stream>>>(ws);
  k_lsm3   <<<dim3(125, BB),  256, 0, stream>>>(b2, ws, out + OUT_VOCAB);
}

// Round 2
// 941.752 us; speedup vs baseline: 1.0474x; 1.0474x over previous
//
#include <hip/hip_runtime.h>
#include <math.h>

#define BB 32
#define NN 32
#define XSS 256
#define KSS 128
#define DD 1024
#define VV 32000
#define TAU_INV 10000.0f

typedef int mask_t;  // bool inputs delivered as int32 (validated round 1)

// ---- workspace layout (float offsets) ----
#define WS_MEANX   0                       // 32*1024
#define WS_MEANY   32768                   // 32*1024
#define WS_MEANK   65536                   // 32*32*1024
#define WS_XCATY   1114112                 // 32*1024
#define WS_VPRE    1146880                 // 32*1024
#define WS_NNZ_CNT 1179648                 // int[32]
#define WS_NNZ_IDX 1179680                 // int[32*32]
#define WS_NNZ_W   1180704                 // float[32*32]
#define WS_LSM_M   1181728                 // float[32*16]
#define WS_LSM_S   1182240                 // float[32*16]
#define WS_VP0     1183744                 // float[32*32000] vocab partial (e-half 0)
#define WS_VP1     2207744                 // float[32*32000] vocab partial (e-half 1)

// ---- output layout (float offsets) ----
#define OUT_PRIOR  0
#define OUT_POST   (BB*NN)
#define OUT_KIDX   (2*BB*NN)
#define OUT_SEL    (3*BB*NN)
#define OUT_VOCAB  (3*BB*NN + BB*KSS*DD)

__device__ __forceinline__ float dot4(float4 a, float4 b) {
  return a.x*b.x + a.y*b.y + a.z*b.z + a.w*b.w;
}
__device__ __forceinline__ void fma4(float4& a, float w, float4 v) {
  a.x += w*v.x; a.y += w*v.y; a.z += w*v.z; a.w += w*v.w;
}

// mean_X / mean_Y: grid (4 chunks, 32 b, 2 which), block 256. Branchless
// weighted accumulate (mask staged in LDS) -> unroll-4 keeps loads in flight.
__global__ void k_meanxy(const float4* __restrict__ U, const float4* __restrict__ R,
                         const mask_t* __restrict__ um, const mask_t* __restrict__ rm,
                         float* __restrict__ ws) {
  const int chunk = blockIdx.x, b = blockIdx.y, which = blockIdx.z, t = threadIdx.x;
  const float4* src = which ? R : U;
  const mask_t* m = which ? rm : um;
  float* dst = ws + (which ? WS_MEANY : WS_MEANX) + b * DD;
  __shared__ float wmask[64];
  const int x0 = chunk * 64;
  if (t < 64) wmask[t] = m[b * XSS + x0 + t] ? 0.f : 1.f;
  __syncthreads();
  float4 acc = make_float4(0.f, 0.f, 0.f, 0.f);
  #pragma unroll 4
  for (int i = 0; i < 64; ++i) {
    float4 v = src[((x0 + i) * BB + b) * (DD/4) + t];
    fma4(acc, wmask[i], v);
  }
  const float s = 1.0f / XSS;
  atomicAdd(&dst[t*4+0], acc.x * s);
  atomicAdd(&dst[t*4+1], acc.y * s);
  atomicAdd(&dst[t*4+2], acc.z * s);
  atomicAdd(&dst[t*4+3], acc.w * s);
}

// mean_K: grid (N, B), block 256. Dominant kernel (537 MB stream).
// Ballot-compact unmasked seq rows into LDS, then branch-free unroll-4 loop.
__global__ void k_meank(const float4* __restrict__ K, const mask_t* __restrict__ km,
                        float* __restrict__ ws) {
  const int n = blockIdx.x, b = blockIdx.y, t = threadIdx.x;
  const int lane = t & 63, wid = t >> 6;
  __shared__ int idx[KSS];
  __shared__ int wcnt[2];
  const mask_t* mrow = km + (b * NN + n) * KSS;
  bool keep = false; int pre = 0;
  if (t < KSS) {  // waves 0,1 fully active
    keep = !mrow[t];
    unsigned long long mb = __ballot(keep);
    pre = __popcll(mb & ((1ull << lane) - 1ull));
    if (lane == 0) wcnt[wid] = __popcll(mb);
  }
  __syncthreads();
  if (t < KSS && keep) {
    const int base = wid ? wcnt[0] : 0;
    idx[base + pre] = t;
  }
  __syncthreads();
  const int cnt = wcnt[0] + wcnt[1];
  const float4* Kb = K + (size_t)b * (DD/4);
  const size_t srow = (size_t)BB * (DD/4);
  float4 a = make_float4(0.f, 0.f, 0.f, 0.f);
  int j = 0;
  for (; j + 4 <= cnt; j += 4) {
    const int s0 = idx[j], s1 = idx[j+1], s2 = idx[j+2], s3 = idx[j+3];
    float4 v0 = Kb[(size_t)(n*KSS + s0) * srow + t];
    float4 v1 = Kb[(size_t)(n*KSS + s1) * srow + t];
    float4 v2 = Kb[(size_t)(n*KSS + s2) * srow + t];
    float4 v3 = Kb[(size_t)(n*KSS + s3) * srow + t];
    a.x += (v0.x + v1.x) + (v2.x + v3.x);
    a.y += (v0.y + v1.y) + (v2.y + v3.y);
    a.z += (v0.z + v1.z) + (v2.z + v3.z);
    a.w += (v0.w + v1.w) + (v2.w + v3.w);
  }
  for (; j < cnt; ++j) {
    float4 v = Kb[(size_t)(n*KSS + idx[j]) * srow + t];
    a.x += v.x; a.y += v.y; a.z += v.z; a.w += v.w;
  }
  const float sc = 1.0f / KSS;
  ((float4*)(ws + WS_MEANK))[(b * NN + n) * (DD/4) + t] =
      make_float4(a.x*sc, a.y*sc, a.z*sc, a.w*sc);
}

// X_cat_Y = concat(meanX, meanY) @ W1.T + b1 as an LDS-tiled mini-GEMM.
// grid 64 (16 d-rows each), block 256 = 16d x 16bgrp, thread tile 1d x 2b.
__global__ void k_xcaty(const float4* __restrict__ W1, const float* __restrict__ b1,
                        float* __restrict__ ws) {
  __shared__ float4 xys[32][33];  // 32 b x 32 f4 of k-chunk (+1 pad)
  __shared__ float4 w1s[16][33];  // 16 d x 32 f4
  const int t = threadIdx.x;
  const int d0 = blockIdx.x * 16;
  const int dl = t >> 4, bg = t & 15;
  const float4* mx = (const float4*)(ws + WS_MEANX);
  const float4* my = (const float4*)(ws + WS_MEANY);
  float acc[2] = {0.f, 0.f};
  for (int c = 0; c < 16; ++c) {           // k-chunks of 128 floats (32 f4)
    #pragma unroll
    for (int i = 0; i < 4; ++i) {
      const int f = t + 256 * i;
      const int br = f >> 5, q = f & 31;
      const int kf4 = c * 32 + q;          // 0..511 over cat(k)
      xys[br][q] = (kf4 < 256) ? mx[br * 256 + kf4] : my[br * 256 + (kf4 - 256)];
    }
    #pragma unroll
    for (int i = 0; i < 2; ++i) {
      const int f = t + 256 * i;
      const int dr = f >> 5, q = f & 31;
      w1s[dr][q] = W1[(d0 + dr) * (2*DD/4) + c * 32 + q];
    }
    __syncthreads();
    #pragma unroll
    for (int q = 0; q < 32; ++q) {
      const float4 wv = w1s[dl][q];
      acc[0] += dot4(wv, xys[bg*2+0][q]);
      acc[1] += dot4(wv, xys[bg*2+1][q]);
    }
    __syncthreads();
  }
  const float bias = b1[d0 + dl];
  ws[WS_XCATY + (bg*2+0) * DD + d0 + dl] = acc[0] + bias;
  ws[WS_XCATY + (bg*2+1) * DD + d0 + dl] = acc[1] + bias;
}

// per-b fused: prior, posterior, K_index, vocab_pre, nnz list. grid 32, block 256.
// wave-per-n dot products (no syncs in the loop).
__global__ void k_small(const float* __restrict__ gumbel, float* __restrict__ ws,
                        float* __restrict__ out) {
  const int b = blockIdx.x, t = threadIdx.x;
  const int lane = t & 63, wid = t >> 6;
  __shared__ float plp[NN], plq[NN], kw[NN];
  __shared__ float scal[3];  // lse1, m2, s2
  __shared__ int   nnz_idx_s[NN];
  __shared__ float nnz_w_s[NN];
  __shared__ int   nnz_cnt_s;

  const float4* mk = (const float4*)(ws + WS_MEANK) + b * NN * (DD/4);
  const float4* mx = (const float4*)(ws + WS_MEANX) + b * (DD/4);
  const float4* xy = (const float4*)(ws + WS_XCATY) + b * (DD/4);

  for (int n = wid; n < NN; n += 4) {
    float pp = 0.f, qq = 0.f;
    #pragma unroll
    for (int r = 0; r < 4; ++r) {
      const int q = r * 64 + lane;
      const float4 mkv = mk[n * (DD/4) + q];
      pp += dot4(mkv, mx[q]);
      qq += dot4(mkv, xy[q]);
    }
    for (int off = 32; off > 0; off >>= 1) {
      pp += __shfl_down(pp, off);
      qq += __shfl_down(qq, off);
    }
    if (lane == 0) { plp[n] = pp; plq[n] = qq; }
  }
  __syncthreads();

  if (t == 0) {
    float z[NN];
    float m1 = -1e30f, m2 = -1e30f, m3 = -1e30f;
    for (int n = 0; n < NN; ++n) {
      m1 = fmaxf(m1, plp[n]);
      m2 = fmaxf(m2, plq[n]);
      z[n] = plq[n] + gumbel[b * NN + n];
      m3 = fmaxf(m3, z[n]);
    }
    float s1 = 0.f, s2 = 0.f, s3 = 0.f;
    for (int n = 0; n < NN; ++n) {
      s1 += expf(plp[n] - m1);
      s2 += expf(plq[n] - m2);
      float w = expf((z[n] - m3) * TAU_INV);
      kw[n] = w;
      s3 += w;
    }
    scal[0] = m1 + logf(s1);
    scal[1] = m2;
    scal[2] = s2;
    const float inv3 = 1.0f / s3;
    int cnt = 0;
    for (int n = 0; n < NN; ++n) {
      kw[n] *= inv3;
      if (kw[n] > 0.f) { nnz_idx_s[cnt] = n; nnz_w_s[cnt] = kw[n]; ++cnt; }
    }
    nnz_cnt_s = cnt;
    ((int*)(ws + WS_NNZ_CNT))[b] = cnt;
    for (int j = 0; j < cnt; ++j) {
      ((int*)(ws + WS_NNZ_IDX))[b * NN + j] = nnz_idx_s[j];
      ws[WS_NNZ_W + b * NN + j] = nnz_w_s[j];
    }
  }
  __syncthreads();

  if (t < NN) {
    out[OUT_PRIOR + b * NN + t] = plp[t] - scal[0];
    out[OUT_POST  + b * NN + t] = expf(plq[t] - scal[1]) / scal[2];
    out[OUT_KIDX  + b * NN + t] = kw[t];
  }

  float4 acc = make_float4(0.f, 0.f, 0.f, 0.f);
  const int cnt = nnz_cnt_s;
  for (int j = 0; j < cnt; ++j) {
    const float w = nnz_w_s[j];
    fma4(acc, w, mk[nnz_idx_s[j] * (DD/4) + t]);
  }
  ((float4*)(ws + WS_VPRE))[b * (DD/4) + t] = acc;
}

// selected_K: grid (KS, B), block 256; gather only nonzero-weight n's.
__global__ void k_selected(const float4* __restrict__ K, const mask_t* __restrict__ km,
                           const float* __restrict__ ws, float4* __restrict__ outsel) {
  const int s = blockIdx.x, b = blockIdx.y, t = threadIdx.x;
  const int cnt = ((const int*)(ws + WS_NNZ_CNT))[b];
  float4 acc = make_float4(0.f, 0.f, 0.f, 0.f);
  for (int j = 0; j < cnt; ++j) {
    const int n = ((const int*)(ws + WS_NNZ_IDX))[b * NN + j];
    const float w = ws[WS_NNZ_W + b * NN + j];
    if (!km[(b * NN + n) * KSS + s]) {
      fma4(acc, w, K[((n * KSS + s) * BB + b) * (DD/4) + t]);
    }
  }
  outsel[(b * KSS + s) * (DD/4) + t] = acc;
}

// vocab GEMM: partial[b,v] = dot(vpre[b][half], W2[v][half]) -> WS_VP0/VP1.
// grid (125, 2), block 256. Tile 256v x 32b, thread tile 8v x 4b. No atomics.
__global__ void __launch_bounds__(256) k_vocab(const float4* __restrict__ W2,
                                               float* __restrict__ ws) {
  const int t = threadIdx.x;
  const int V0 = blockIdx.x * 256;
  const int e4_base = blockIdx.y * 128;   // float4 units (512 floats per half)
  float* part = ws + (blockIdx.y ? WS_VP1 : WS_VP0);
  __shared__ float4 w2s[256 * 9];
  __shared__ float4 pres[32 * 9];
  const float4* vp = (const float4*)(ws + WS_VPRE);
  const int vlane = t & 31, bgrp = t >> 5;

  float acc[8][4];
  #pragma unroll
  for (int k = 0; k < 8; ++k)
    #pragma unroll
    for (int j = 0; j < 4; ++j) acc[k][j] = 0.f;

  for (int e4 = e4_base; e4 < e4_base + 128; e4 += 8) {
    #pragma unroll
    for (int k = 0; k < 8; ++k) {
      const int f = t + 256 * k;
      const int vr = f >> 3, q = f & 7;
      w2s[vr * 9 + q] = W2[(V0 + vr) * (DD/4) + e4 + q];
    }
    {
      const int br = t >> 3, q = t & 7;
      pres[br * 9 + q] = vp[br * (DD/4) + e4 + q];
    }
    __syncthreads();
    #pragma unroll
    for (int q = 0; q < 8; ++q) {
      float4 pb[4];
      #pragma unroll
      for (int j = 0; j < 4; ++j) pb[j] = pres[(bgrp + 8 * j) * 9 + q];
      #pragma unroll
      for (int k = 0; k < 8; ++k) {
        float4 wv = w2s[(vlane + 32 * k) * 9 + q];
        #pragma unroll
        for (int j = 0; j < 4; ++j) acc[k][j] += dot4(wv, pb[j]);
      }
    }
    __syncthreads();
  }
  #pragma unroll
  for (int k = 0; k < 8; ++k)
    #pragma unroll
    for (int j = 0; j < 4; ++j)
      part[(bgrp + 8 * j) * VV + V0 + vlane + 32 * k] = acc[k][j];
}

// log_softmax pass 1: partial max/sumexp of x = p0+p1+b2 per (b, chunk).
__global__ void k_lsm1(const float* __restrict__ b2, float* __restrict__ ws) {
  const int c = blockIdx.x, b = blockIdx.y, t = threadIdx.x;
  const int lane = t & 63, wid = t >> 6;
  const float* p0 = ws + WS_VP0 + b * VV + c * 2000;
  const float* p1 = ws + WS_VP1 + b * VV + c * 2000;
  const float* bb = b2 + c * 2000;
  __shared__ float red[4];
  float xv[8];
  int cnt = 0;
  float m = -1e30f;
  for (int i = t; i < 2000; i += 256) {
    float x = p0[i] + p1[i] + bb[i];
    xv[cnt++] = x;
    m = fmaxf(m, x);
  }
  for (int off = 32; off > 0; off >>= 1) m = fmaxf(m, __shfl_down(m, off));
  if (lane == 0) red[wid] = m;
  __syncthreads();
  if (t == 0) red[0] = fmaxf(fmaxf(red[0], red[1]), fmaxf(red[2], red[3]));
  __syncthreads();
  const float M = red[0];
  __syncthreads();
  float s = 0.f;
  for (int i = 0; i < cnt; ++i) s += expf(xv[i] - M);
  for (int off = 32; off > 0; off >>= 1) s += __shfl_down(s, off);
  if (lane == 0) red[wid] = s;
  __syncthreads();
  if (t == 0) {
    ws[WS_LSM_M + b * 16 + c] = M;
    ws[WS_LSM_S + b * 16 + c] = red[0] + red[1] + red[2] + red[3];
  }
}

// finalize: combine chunk partials -> lse[b] (in-block), out = p0+p1+b2-lse.
__global__ void k_lsm3(const float* __restrict__ b2, const float* __restrict__ ws,
                       float* __restrict__ logits) {
  const int b = blockIdx.y, t = threadIdx.x;
  __shared__ float lse_s;
  if (t == 0) {
    float M = -1e30f;
    for (int c = 0; c < 16; ++c) M = fmaxf(M, ws[WS_LSM_M + b * 16 + c]);
    float S = 0.f;
    for (int c = 0; c < 16; ++c)
      S += ws[WS_LSM_S + b * 16 + c] * expf(ws[WS_LSM_M + b * 16 + c] - M);
    lse_s = M + logf(S);
  }
  __syncthreads();
  const int v = blockIdx.x * 256 + t;
  logits[b * VV + v] = ws[WS_VP0 + b * VV + v] + ws[WS_VP1 + b * VV + v]
                       + b2[v] - lse_s;
}

extern "C" void kernel_launch(void* const* d_in, const int* in_sizes, int n_in,
                              void* d_out, int out_size, void* d_ws, size_t ws_size,
                              hipStream_t stream) {
  const float4* U  = (const float4*)d_in[0];
  const float4* R  = (const float4*)d_in[1];
  const float4* K  = (const float4*)d_in[2];
  const mask_t* um = (const mask_t*)d_in[3];
  const mask_t* rm = (const mask_t*)d_in[4];
  const mask_t* km = (const mask_t*)d_in[5];
  const float* g   = (const float*)d_in[6];
  const float4* W1 = (const float4*)d_in[7];
  const float* b1  = (const float*)d_in[8];
  const float4* W2 = (const float4*)d_in[9];
  const float* b2  = (const float*)d_in[10];
  float* out = (float*)d_out;
  float* ws  = (float*)d_ws;

  hipMemsetAsync(ws + WS_MEANX, 0, 2 * BB * DD * sizeof(float), stream);

  k_meanxy  <<<dim3(4, 32, 2), 256, 0, stream>>>(U, R, um, rm, ws);
  k_meank   <<<dim3(NN, BB),   256, 0, stream>>>(K, km, ws);
  k_xcaty   <<<dim3(64),       256, 0, stream>>>(W1, b1, ws);
  k_small   <<<dim3(BB),       256, 0, stream>>>(g, ws, out);
  k_selected<<<dim3(KSS, BB),  256, 0, stream>>>(K, km, ws, (float4*)(out + OUT_SEL));
  k_vocab   <<<dim3(125, 2),   256, 0, stream>>>(W2, ws);
  k_lsm1    <<<dim3(16, BB),   256, 0, stream>>>(b2, ws);
  k_lsm3    <<<dim3(125, BB),  256, 0, stream>>>(b2, ws, out + OUT_VOCAB);
}